// Round 5
// baseline (143.814 us; speedup 1.0000x reference)
//
#include <hip/hip_runtime.h>

// WaveletLayer: db2 DWT -> gain -> IDWT -> ReLU, fused 6-tap stencil.
// v5: 2 contiguous quads per thread (8 outputs, 80 B/lane useful payload).
// 2x dwordx4 x-loads + 1x dwordx4 ker load + 2x nt dwordx4 stores per
// thread; halves wave count and shuffle/waitcnt chains per byte vs v2.
// Shared cA/cD at the quad boundary computed once. Halo via cross-lane
// shuffles with predicated lane-0/63 edge loads (verified v2 mapping).

#define NN 4096
#define LL 2049
#define QPR 512    // quad-pairs per row; thread q handles quads 2q, 2q+1
#define TPB 256

typedef float v4f  __attribute__((ext_vector_type(4)));
// ker rows have stride 2049 floats (8196 B): 16B vector loads are only
// 4-byte aligned on odd rows -> use an align(4) vector type (legal, HW
// supports dword-aligned dwordx4).
typedef float v4fu __attribute__((ext_vector_type(4), aligned(4)));

__global__ __launch_bounds__(TPB) void wavelet_fused(const float* __restrict__ x,
                                                     const float* __restrict__ ker,
                                                     float* __restrict__ out) {
    const int row  = blockIdx.y;
    const int q    = blockIdx.x * TPB + threadIdx.x;   // 0..511 quad-pair index
    const int lane = threadIdx.x & 63;

    // db2 decomposition taps
    const float lo0 = -0.12940952255126037f, lo1 = 0.22414386804185735f,
                lo2 =  0.8365163037378079f,  lo3 = 0.48296291314453416f;
    const float hi0 = -0.48296291314453416f, hi1 = 0.8365163037378079f,
                hi2 = -0.22414386804185735f, hi3 = -0.12940952255126037f;

    const v4f*   x4   = (const v4f*)(x + (size_t)row * NN);
    const float* krow = ker + (size_t)row * LL;

    // own data: elements 8q..8q+7 and gains g[4q..4q+3]
    const v4f vA = x4[2 * q];
    const v4f vB = x4[2 * q + 1];
    const v4fu gv = *(const v4fu*)(krow + 4 * q);
    const float g0 = gv.x, g1 = gv.y, g2 = gv.z, g3 = gv.w;

    // wave-edge halo (predicated: only lanes 0/63 issue loads)
    float ha = 0.0f, hb = 0.0f, hg = 0.0f;
    if (lane == 0) {
        const v4f vp = x4[(q > 0) ? (2 * q - 1) : 0];
        ha = vp.z; hb = vp.w;                          // X(8q-2), X(8q-1)
    } else if (lane == 63) {
        const v4f vn = x4[(q < QPR - 1) ? (2 * q + 2) : (2 * q + 1)];
        ha = vn.x; hb = vn.y;                          // X(8q+8), X(8q+9)
        hg = krow[4 * q + 4];                          // g[4q+4] (<= 2048, valid)
    }

    // interior halo via cross-lane shuffles (lanes are consecutive q, waves
    // never straddle rows: blockIdx.y fixes the row)
    float e0  = __shfl_up(vB.z, 1);    // prev thread's X(8q-2)
    float e1  = __shfl_up(vB.w, 1);    // prev thread's X(8q-1)
    float e10 = __shfl_down(vA.x, 1);  // next thread's X(8q+8)
    float e11 = __shfl_down(vA.y, 1);  // next thread's X(8q+9)
    float g4  = __shfl_down(g0, 1);    // g[4q+4] = next thread's g0

    if (lane == 0)  { e0 = ha; e1 = hb; }
    if (lane == 63) { e10 = ha; e11 = hb; g4 = hg; }
    // symmetric-padding boundary overrides (verified mapping)
    if (q == 0)       { e0 = vA.y;  e1 = vA.x; }   // X(-2)=x[1], X(-1)=x[0]
    if (q == QPR - 1) { e10 = vB.w; e11 = vB.z; }  // X(4096)=x[4095], X(4097)=x[4094]

    // analysis: cA[m] = lo3*X(2m-2)+lo2*X(2m-1)+lo1*X(2m)+lo0*X(2m+1), m=4q..4q+4
    const float cA0 = lo3 * e0   + lo2 * e1   + lo1 * vA.x + lo0 * vA.y;
    const float cD0 = hi3 * e0   + hi2 * e1   + hi1 * vA.x + hi0 * vA.y;
    const float cA1 = lo3 * vA.x + lo2 * vA.y + lo1 * vA.z + lo0 * vA.w;
    const float cD1 = hi3 * vA.x + hi2 * vA.y + hi1 * vA.z + hi0 * vA.w;
    const float cA2 = lo3 * vA.z + lo2 * vA.w + lo1 * vB.x + lo0 * vB.y;
    const float cD2 = hi3 * vA.z + hi2 * vA.w + hi1 * vB.x + hi0 * vB.y;
    const float cA3 = lo3 * vB.x + lo2 * vB.y + lo1 * vB.z + lo0 * vB.w;
    const float cD3 = hi3 * vB.x + hi2 * vB.y + hi1 * vB.z + hi0 * vB.w;
    const float cA4 = lo3 * vB.z + lo2 * vB.w + lo1 * e10  + lo0 * e11;
    const float cD4 = hi3 * vB.z + hi2 * vB.w + hi1 * e10  + hi0 * e11;

    const float A0 = g0 * cA0, D0 = g0 * cD0;
    const float A1 = g1 * cA1, D1 = g1 * cD1;
    const float A2 = g2 * cA2, D2 = g2 * cD2;
    const float A3 = g3 * cA3, D3 = g3 * cD3;
    const float A4 = g4 * cA4, D4 = g4 * cD4;

    // synthesis: y[2m]   = lo1*A[m]+lo3*A[m+1]+hi1*D[m]+hi3*D[m+1]
    //            y[2m+1] = lo0*A[m]+lo2*A[m+1]+hi0*D[m]+hi2*D[m+1]
    const float y0 = lo1 * A0 + lo3 * A1 + hi1 * D0 + hi3 * D1;
    const float y1 = lo0 * A0 + lo2 * A1 + hi0 * D0 + hi2 * D1;
    const float y2 = lo1 * A1 + lo3 * A2 + hi1 * D1 + hi3 * D2;
    const float y3 = lo0 * A1 + lo2 * A2 + hi0 * D1 + hi2 * D2;
    const float y4 = lo1 * A2 + lo3 * A3 + hi1 * D2 + hi3 * D3;
    const float y5 = lo0 * A2 + lo2 * A3 + hi0 * D2 + hi2 * D3;
    const float y6 = lo1 * A3 + lo3 * A4 + hi1 * D3 + hi3 * D4;
    const float y7 = lo0 * A3 + lo2 * A4 + hi0 * D3 + hi2 * D4;

    v4f r0, r1;
    r0.x = fmaxf(y0, 0.0f); r0.y = fmaxf(y1, 0.0f);
    r0.z = fmaxf(y2, 0.0f); r0.w = fmaxf(y3, 0.0f);
    r1.x = fmaxf(y4, 0.0f); r1.y = fmaxf(y5, 0.0f);
    r1.z = fmaxf(y6, 0.0f); r1.w = fmaxf(y7, 0.0f);

    v4f* out4 = (v4f*)(out + (size_t)row * NN);
    __builtin_nontemporal_store(r0, out4 + 2 * q);
    __builtin_nontemporal_store(r1, out4 + 2 * q + 1);
}

extern "C" void kernel_launch(void* const* d_in, const int* in_sizes, int n_in,
                              void* d_out, int out_size, void* d_ws, size_t ws_size,
                              hipStream_t stream) {
    const float* x   = (const float*)d_in[0];
    const float* ker = (const float*)d_in[1];
    float* out = (float*)d_out;
    wavelet_fused<<<dim3(QPR / TPB, 4096), dim3(TPB), 0, stream>>>(x, ker, out);
}

// Round 6
// 137.457 us; speedup vs baseline: 1.0462x; 1.0462x over previous
//
#include <hip/hip_runtime.h>

// WaveletLayer: db2 DWT -> gain -> IDWT -> ReLU, fused into a single 6-tap
// stencil. y[2m],y[2m+1] depend only on x[2m-2..2m+3] (symmetric-padded) and
// g[m],g[m+1]. No LDS, no barriers: 3 overlapping aligned float4 x-loads per
// thread (L1 dedupes), float4 stores. B=4096 rows, N=4096, L=2049.
//
// FINAL (v6 = revert to round-0 best): six structural variants measured
// (shuffle-halo, 4-quad batch, persistent grid-stride, 8-wide payload, nt
// stores) — all null or negative. Dispatch time is structure-invariant at
// ~43 us with FETCH=51.7MB / WRITE=65.5MB: 3-stream mixed R/W equilibrium
// of the memory system, not a kernel artifact. This is the empirical best.

#define NN 4096
#define LL 2049
#define PAIRS4 1024  // threads-tasks per row: each handles 4 outputs

__global__ __launch_bounds__(256) void wavelet_fused(const float* __restrict__ x,
                                                     const float* __restrict__ ker,
                                                     float* __restrict__ out) {
    const int row = blockIdx.y;
    const int t   = blockIdx.x * 256 + threadIdx.x;   // 0..1023: output quad index

    // db2 decomposition taps
    const float lo0 = -0.12940952255126037f, lo1 = 0.22414386804185735f,
                lo2 =  0.8365163037378079f,  lo3 = 0.48296291314453416f;
    const float hi0 = -0.48296291314453416f, hi1 = 0.8365163037378079f,
                hi2 = -0.22414386804185735f, hi3 = -0.12940952255126037f;

    const float4* x4 = (const float4*)(x + (size_t)row * NN);

    // x window X(4t-2 .. 4t+5); X(i) = x[sym_map(i)]
    const int tp = (t == 0) ? 0 : (t - 1);
    const int tn = (t == PAIRS4 - 1) ? t : (t + 1);
    const float4 vp = x4[tp];
    const float4 vc = x4[t];
    const float4 vn = x4[tn];

    // interior: e0..e7 = prev.z, prev.w, cur.xyzw, next.x, next.y
    const bool first = (t == 0);
    const bool last  = (t == PAIRS4 - 1);
    const float e0 = first ? vc.y : vp.z;   // X(-2) = x[1]
    const float e1 = first ? vc.x : vp.w;   // X(-1) = x[0]
    const float e2 = vc.x;
    const float e3 = vc.y;
    const float e4 = vc.z;
    const float e5 = vc.w;
    const float e6 = last ? vc.w : vn.x;    // X(4096) = x[4095]
    const float e7 = last ? vc.z : vn.y;    // X(4097) = x[4094]

    // gains g[2t], g[2t+1], g[2t+2]  (2t+2 <= 2048 = LL-1, always valid)
    const float* krow = ker + (size_t)row * LL;
    const float g0 = krow[2 * t];
    const float g1 = krow[2 * t + 1];
    const float g2 = krow[2 * t + 2];

    // analysis: cA[j] = lo3*X(2j-2)+lo2*X(2j-1)+lo1*X(2j)+lo0*X(2j+1)
    const float cA0 = lo3 * e0 + lo2 * e1 + lo1 * e2 + lo0 * e3;
    const float cD0 = hi3 * e0 + hi2 * e1 + hi1 * e2 + hi0 * e3;
    const float cA1 = lo3 * e2 + lo2 * e3 + lo1 * e4 + lo0 * e5;
    const float cD1 = hi3 * e2 + hi2 * e3 + hi1 * e4 + hi0 * e5;
    const float cA2 = lo3 * e4 + lo2 * e5 + lo1 * e6 + lo0 * e7;
    const float cD2 = hi3 * e4 + hi2 * e5 + hi1 * e6 + hi0 * e7;

    const float A0 = g0 * cA0, D0 = g0 * cD0;
    const float A1 = g1 * cA1, D1 = g1 * cD1;
    const float A2 = g2 * cA2, D2 = g2 * cD2;

    // synthesis: y[2m] = lo1*A[m]+lo3*A[m+1]+hi1*D[m]+hi3*D[m+1]
    //            y[2m+1] = lo0*A[m]+lo2*A[m+1]+hi0*D[m]+hi2*D[m+1]
    float y0 = lo1 * A0 + lo3 * A1 + hi1 * D0 + hi3 * D1;
    float y1 = lo0 * A0 + lo2 * A1 + hi0 * D0 + hi2 * D1;
    float y2 = lo1 * A1 + lo3 * A2 + hi1 * D1 + hi3 * D2;
    float y3 = lo0 * A1 + lo2 * A2 + hi0 * D1 + hi2 * D2;

    y0 = fmaxf(y0, 0.0f);
    y1 = fmaxf(y1, 0.0f);
    y2 = fmaxf(y2, 0.0f);
    y3 = fmaxf(y3, 0.0f);

    float4* out4 = (float4*)(out + (size_t)row * NN);
    out4[t] = make_float4(y0, y1, y2, y3);
}

extern "C" void kernel_launch(void* const* d_in, const int* in_sizes, int n_in,
                              void* d_out, int out_size, void* d_ws, size_t ws_size,
                              hipStream_t stream) {
    const float* x   = (const float*)d_in[0];
    const float* ker = (const float*)d_in[1];
    float* out = (float*)d_out;
    wavelet_fused<<<dim3(PAIRS4 / 256, 4096), dim3(256), 0, stream>>>(x, ker, out);
}